// Round 3
// baseline (1025.631 us; speedup 1.0000x reference)
//
#include <hip/hip_runtime.h>
#include <hip/hip_bf16.h>
#include <cstdint>
#include <cstddef>

#define NTOK 4096
#define EMB 1024
#define HID 4096
#define NEXP 8
#define RTR_BLOCKS 256  // router blocks (16 tokens each)

typedef __bf16 bf16x8_t __attribute__((ext_vector_type(8)));
typedef __bf16 bf16x4_t __attribute__((ext_vector_type(4)));
typedef float  f32x4_t  __attribute__((ext_vector_type(4)));

// async 16B global->LDS (direct-to-LDS DMA; LDS dest = wave-uniform base + lane*16)
__device__ __forceinline__ void gll16(const void* g, void* l) {
    __builtin_amdgcn_global_load_lds(
        (const __attribute__((address_space(1))) void*)g,
        (__attribute__((address_space(3))) void*)l, 16, 0, 0);
}

// ---------------- router: scores, top-2, softmax; per-block partials ----------------
__global__ __launch_bounds__(256) void router_kernel(
    const float* __restrict__ x, const float* __restrict__ gw,
    int* __restrict__ topk_idx, float* __restrict__ topk_prob,
    int* __restrict__ pcount, float* __restrict__ pprob)
{
    __shared__ int cs[8];
    __shared__ float ps[8];
    const int tid = threadIdx.x;
    if (tid < 8) { cs[tid] = 0; ps[tid] = 0.f; }
    __syncthreads();
    const int lane = tid & 63, wave = tid >> 6;
#pragma unroll
    for (int it = 0; it < 4; ++it) {
        const int t = blockIdx.x * 16 + wave * 4 + it;
        const float* xr = x + (size_t)t * EMB;
        float xv[16];
#pragma unroll
        for (int i = 0; i < 16; i++) xv[i] = xr[lane + 64 * i];
        float sc[8];
#pragma unroll
        for (int e = 0; e < 8; e++) {
            const float* g = gw + (size_t)e * EMB;
            float a = 0.f;
#pragma unroll
            for (int i = 0; i < 16; i++) a += xv[i] * g[lane + 64 * i];
            sc[e] = a;
        }
#pragma unroll
        for (int off = 32; off; off >>= 1)
#pragma unroll
            for (int e = 0; e < 8; e++) sc[e] += __shfl_xor(sc[e], off, 64);
        if (lane == 0) {
            int j0 = 0; float s0 = sc[0];
            for (int e = 1; e < 8; e++) if (sc[e] > s0) { s0 = sc[e]; j0 = e; }
            int j1 = -1; float s1 = -1e30f;
            for (int e = 0; e < 8; e++) if (e != j0 && sc[e] > s1) { s1 = sc[e]; j1 = e; }
            float r = __expf(s1 - s0);
            float p0 = 1.0f / (1.0f + r);
            float p1 = r * p0;
            topk_idx[2 * t] = j0;  topk_idx[2 * t + 1] = j1;
            topk_prob[2 * t] = p0; topk_prob[2 * t + 1] = p1;
            atomicAdd(&cs[j0], 1);
            atomicAdd(&cs[j1], 1);
            float pe[8]; float sum = 0.f;
            for (int e = 0; e < 8; e++) { pe[e] = __expf(sc[e] - s0); sum += pe[e]; }
            float inv = 1.0f / sum;
            for (int e = 0; e < 8; e++) atomicAdd(&ps[e], pe[e] * inv);
        }
    }
    __syncthreads();
    if (tid < 8) {
        pcount[blockIdx.x * 8 + tid] = cs[tid];
        pprob[blockIdx.x * 8 + tid]  = ps[tid];
    }
}

// ---------------- scan ----------------
__global__ void scan_kernel(const int* __restrict__ pcount, const float* __restrict__ pprob,
                            int* __restrict__ counts, int* __restrict__ offsets,
                            float* __restrict__ aux_out)
{
    __shared__ int cs[8]; __shared__ float ps[8];
    const int tid = threadIdx.x;
    if (tid < 8) {
        int c = 0; float p = 0.f;
        for (int b = 0; b < RTR_BLOCKS; ++b) { c += pcount[b * 8 + tid]; p += pprob[b * 8 + tid]; }
        counts[tid] = c; cs[tid] = c; ps[tid] = p;
    }
    __syncthreads();
    if (tid == 0) {
        int off = 0; float aux = 0.f;
        for (int e = 0; e < 8; e++) { offsets[e] = off; off += cs[e]; aux += (float)cs[e] * ps[e]; }
        *aux_out = aux * 8.0f / ((float)NTOK * (float)NTOK);
    }
}

// ---------------- scatter: ballot-aggregated cursor atomics ----------------
__global__ __launch_bounds__(256) void scatter_kernel(
    const int* __restrict__ topk_idx, const float* __restrict__ topk_prob,
    const int* __restrict__ offsets, int* __restrict__ cursor,
    int* __restrict__ row_tok, float* __restrict__ row_prob)
{
    const int t = blockIdx.x * 256 + threadIdx.x;
    const int lane = threadIdx.x & 63;
    const unsigned long long mylt = (lane == 63) ? 0x7fffffffffffffffull : ((1ull << lane) - 1ull);
#pragma unroll
    for (int k = 0; k < 2; k++) {
        const int e = topk_idx[2 * t + k];
        const float p = topk_prob[2 * t + k];
        int base = 0;
        for (int ex = 0; ex < 8; ++ex) {
            unsigned long long m = __ballot(e == ex);
            if (m) {
                int leader = __ffsll((long long)m) - 1;
                int b = 0;
                if (lane == leader) b = atomicAdd(&cursor[ex], (int)__popcll(m));
                b = __shfl(b, leader, 64);
                if (e == ex) base = b + (int)__popcll(m & mylt);
            }
        }
        const int pos = offsets[e] + base;
        row_tok[pos] = t;
        row_prob[pos] = p;
    }
}

// ---------------- fp32 -> bf16 pack (8 elems/thread) ----------------
__global__ void cvt_pack(const float* __restrict__ src, __bf16* __restrict__ dst, int n8)
{
    const int i = blockIdx.x * 256 + threadIdx.x;
    if (i >= n8) return;
    const float4* s = (const float4*)src + (size_t)i * 2;
    float4 u = s[0], v = s[1];
    bf16x8_t o;
    o[0] = (__bf16)u.x; o[1] = (__bf16)u.y; o[2] = (__bf16)u.z; o[3] = (__bf16)u.w;
    o[4] = (__bf16)v.x; o[5] = (__bf16)v.y; o[6] = (__bf16)v.z; o[7] = (__bf16)v.w;
    *(bf16x8_t*)(dst + (size_t)i * 8) = o;
}

// ===== GEMM1: H = silu(Xg W1^T + b1) * (Xg W2^T + b2) =====
// A fragments direct global->reg; B1/B2 via swizzled LDS (chunk slot = (c + (row>>1)) & 3)
__global__ __launch_bounds__(256, 2) void gemm1_bf(
    const __bf16* __restrict__ xbf,
    const __bf16* __restrict__ w1bf, const float* __restrict__ b1,
    const __bf16* __restrict__ w2bf, const float* __restrict__ b2,
    const int* __restrict__ counts, const int* __restrict__ offsets,
    const int* __restrict__ row_tok, __bf16* __restrict__ Hbuf)
{
    const int e = blockIdx.z;
    const int cnt = counts[e];
    const int row0 = blockIdx.y * 128;
    if (row0 >= cnt) return;
    const int seg = offsets[e];
    const int n0 = blockIdx.x * 128;

    __shared__ __align__(16) __bf16 Bs1[128 * 32];
    __shared__ __align__(16) __bf16 Bs2[128 * 32];

    const int tid = threadIdx.x;
    const int lane = tid & 63;
    const int wave = tid >> 6;
    const int r16 = lane >> 2;             // staging row within 16-row block
    const int ra0 = wave * 32 + r16;       // row-in-tile (first 16-row block)
    const int ra1 = ra0 + 16;
    // source chunk permutation: LDS slot (lane&3) holds global chunk ((lane&3)-(row>>1))&3
    const int clog = ((lane & 3) - (ra0 >> 1)) & 3;   // same value for ra1 (+16 rows -> +8 ≡ 0 mod 4)

    const __bf16* b10p = w1bf + ((size_t)e * HID + n0 + ra0) * EMB + clog * 8;
    const __bf16* b11p = w1bf + ((size_t)e * HID + n0 + ra1) * EMB + clog * 8;
    const __bf16* b20p = w2bf + ((size_t)e * HID + n0 + ra0) * EMB + clog * 8;
    const __bf16* b21p = w2bf + ((size_t)e * HID + n0 + ra1) * EMB + clog * 8;

    __bf16* lB10 = &Bs1[(wave * 32) * 32];
    __bf16* lB11 = &Bs1[(wave * 32 + 16) * 32];
    __bf16* lB20 = &Bs2[(wave * 32) * 32];
    __bf16* lB21 = &Bs2[(wave * 32 + 16) * 32];

    const int fr = lane & 15;
    const int quad = lane >> 4;
    const int wm = (wave >> 1) * 64;
    const int wn = (wave & 1) * 64;

    // A: per-fragment-row token bases (gather once)
    const __bf16* aP[4];
#pragma unroll
    for (int i = 0; i < 4; i++) {
        int idx = seg + row0 + wm + i * 16 + fr;
        if (idx > 8191) idx = 8191;                   // all row_tok entries valid
        aP[i] = xbf + (size_t)row_tok[idx] * EMB + quad * 8;
    }

    // swizzled, loop-invariant LDS read offsets for B fragments
    int offB[4];
#pragma unroll
    for (int j = 0; j < 4; j++) {
        int rb = wn + j * 16 + fr;
        offB[j] = rb * 32 + ((quad + (rb >> 1)) & 3) * 8;
    }

    f32x4_t acc1[4][4], acc2[4][4];
#pragma unroll
    for (int i = 0; i < 4; i++)
#pragma unroll
        for (int j = 0; j < 4; j++)
#pragma unroll
            for (int c = 0; c < 4; c++) { acc1[i][j][c] = 0.f; acc2[i][j][c] = 0.f; }

    for (int kk = 0; kk < EMB / 32; ++kk) {
        __syncthreads();                 // previous fragments consumed
        gll16(b10p, lB10); gll16(b11p, lB11);
        gll16(b20p, lB20); gll16(b21p, lB21);
        b10p += 32; b11p += 32; b20p += 32; b21p += 32;
        bf16x8_t av[4];
#pragma unroll
        for (int i = 0; i < 4; i++) { av[i] = *(const bf16x8_t*)aP[i]; aP[i] += 32; }
        __syncthreads();                 // drains vmcnt -> staging + av ready

        bf16x8_t bv1[4], bv2[4];
#pragma unroll
        for (int j = 0; j < 4; j++) bv1[j] = *(const bf16x8_t*)&Bs1[offB[j]];
#pragma unroll
        for (int j = 0; j < 4; j++) bv2[j] = *(const bf16x8_t*)&Bs2[offB[j]];
#pragma unroll
        for (int i = 0; i < 4; i++)
#pragma unroll
            for (int j = 0; j < 4; j++) {
                acc1[i][j] = __builtin_amdgcn_mfma_f32_16x16x32_bf16(av[i], bv1[j], acc1[i][j], 0, 0, 0);
                acc2[i][j] = __builtin_amdgcn_mfma_f32_16x16x32_bf16(av[i], bv2[j], acc2[i][j], 0, 0, 0);
            }
    }

    float b1v[4], b2v[4];
#pragma unroll
    for (int j = 0; j < 4; j++) {
        int nn = n0 + wn + j * 16 + fr;
        b1v[j] = b1[(size_t)e * HID + nn];
        b2v[j] = b2[(size_t)e * HID + nn];
    }
#pragma unroll
    for (int i = 0; i < 4; i++) {
#pragma unroll
        for (int rr = 0; rr < 4; rr++) {
            int grow = row0 + wm + i * 16 + quad * 4 + rr;
            if (grow < cnt) {
                __bf16* hrow = Hbuf + (size_t)(seg + grow) * HID;
#pragma unroll
                for (int j = 0; j < 4; j++) {
                    float c1 = acc1[i][j][rr] + b1v[j];
                    float c2 = acc2[i][j][rr] + b2v[j];
                    float sig = 1.0f / (1.0f + __expf(-c1));
                    hrow[n0 + wn + j * 16 + fr] = (__bf16)(c1 * sig * c2);
                }
            }
        }
    }
}

// ===== GEMM2: out += p * (H W3^T + b3) =====
__global__ __launch_bounds__(256, 2) void gemm2_bf(
    const __bf16* __restrict__ Hbuf,
    const __bf16* __restrict__ w3bf, const float* __restrict__ b3,
    const int* __restrict__ counts, const int* __restrict__ offsets,
    const int* __restrict__ row_tok, const float* __restrict__ row_prob,
    float* __restrict__ out)
{
    const int e = blockIdx.z;
    const int cnt = counts[e];
    const int row0 = blockIdx.y * 128;
    if (row0 >= cnt) return;
    const int seg = offsets[e];
    const int n0 = blockIdx.x * 128;

    __shared__ __align__(16) __bf16 Bs[128 * 32];

    const int tid = threadIdx.x;
    const int lane = tid & 63;
    const int wave = tid >> 6;
    const int r16 = lane >> 2;
    const int ra0 = wave * 32 + r16;
    const int ra1 = ra0 + 16;
    const int clog = ((lane & 3) - (ra0 >> 1)) & 3;

    const __bf16* b0p = w3bf + ((size_t)e * EMB + n0 + ra0) * HID + clog * 8;
    const __bf16* b1p = w3bf + ((size_t)e * EMB + n0 + ra1) * HID + clog * 8;
    __bf16* lB0 = &Bs[(wave * 32) * 32];
    __bf16* lB1 = &Bs[(wave * 32 + 16) * 32];

    const int fr = lane & 15;
    const int quad = lane >> 4;
    const int wm = (wave >> 1) * 64;
    const int wn = (wave & 1) * 64;

    // A direct from Hbuf (rows contiguous; slack rows finite-poison, masked at epilogue)
    const __bf16* aP[4];
#pragma unroll
    for (int i = 0; i < 4; i++)
        aP[i] = Hbuf + (size_t)(seg + row0 + wm + i * 16 + fr) * HID + quad * 8;

    int offB[4];
#pragma unroll
    for (int j = 0; j < 4; j++) {
        int rb = wn + j * 16 + fr;
        offB[j] = rb * 32 + ((quad + (rb >> 1)) & 3) * 8;
    }

    f32x4_t acc[4][4];
#pragma unroll
    for (int i = 0; i < 4; i++)
#pragma unroll
        for (int j = 0; j < 4; j++)
#pragma unroll
            for (int c = 0; c < 4; c++) acc[i][j][c] = 0.f;

    for (int kk = 0; kk < HID / 32; ++kk) {
        __syncthreads();
        gll16(b0p, lB0); gll16(b1p, lB1);
        b0p += 32; b1p += 32;
        bf16x8_t av[4];
#pragma unroll
        for (int i = 0; i < 4; i++) { av[i] = *(const bf16x8_t*)aP[i]; aP[i] += 32; }
        __syncthreads();

        bf16x8_t bv[4];
#pragma unroll
        for (int j = 0; j < 4; j++) bv[j] = *(const bf16x8_t*)&Bs[offB[j]];
#pragma unroll
        for (int i = 0; i < 4; i++)
#pragma unroll
            for (int j = 0; j < 4; j++)
                acc[i][j] = __builtin_amdgcn_mfma_f32_16x16x32_bf16(av[i], bv[j], acc[i][j], 0, 0, 0);
    }

    float b3v[4];
#pragma unroll
    for (int j = 0; j < 4; j++) b3v[j] = b3[(size_t)e * EMB + n0 + wn + j * 16 + fr];
#pragma unroll
    for (int i = 0; i < 4; i++) {
#pragma unroll
        for (int rr = 0; rr < 4; rr++) {
            int grow = row0 + wm + i * 16 + quad * 4 + rr;
            if (grow < cnt) {
                int tok = row_tok[seg + grow];
                float pr = row_prob[seg + grow];
                float* orow = out + (size_t)tok * EMB;
#pragma unroll
                for (int j = 0; j < 4; j++) {
                    float v = pr * (acc[i][j][rr] + b3v[j]);
                    atomicAdd(&orow[n0 + wn + j * 16 + fr], v);
                }
            }
        }
    }
}

extern "C" void kernel_launch(void* const* d_in, const int* in_sizes, int n_in,
                              void* d_out, int out_size, void* d_ws, size_t ws_size,
                              hipStream_t stream)
{
    const float* x  = (const float*)d_in[0];
    const float* gw = (const float*)d_in[1];
    const float* w1 = (const float*)d_in[2];
    const float* b1 = (const float*)d_in[3];
    const float* w2 = (const float*)d_in[4];
    const float* b2 = (const float*)d_in[5];
    const float* w3 = (const float*)d_in[6];
    const float* b3 = (const float*)d_in[7];
    float* out = (float*)d_out;

    char* ws = (char*)d_ws;
    int*   counts    = (int*)(ws + 0);
    int*   offsets   = (int*)(ws + 32);
    int*   cursor    = (int*)(ws + 64);
    int*   topk_idx  = (int*)(ws + 1024);
    float* topk_prob = (float*)(ws + 1024 + 32768);
    int*   row_tok   = (int*)(ws + 1024 + 65536);
    float* row_prob  = (float*)(ws + 1024 + 98304);
    int*   pcount    = (int*)(ws + 1024 + 131072);
    float* pprob     = (float*)(ws + 1024 + 131072 + 8192);
    __bf16* xbf  = (__bf16*)(ws + (1u << 20));            // 8.39 MB
    __bf16* Hbuf = (__bf16*)(ws + (16u << 20));           // (8192+128)*4096 bf16 = 68.2 MB
    __bf16* w1bf = (__bf16*)(ws + 88080384ull);           // 67.1 MB
    __bf16* w2bf = (__bf16*)(ws + 157286400ull);          // 67.1 MB
    __bf16* w3bf = w1bf;                                  // reused after gemm1 completes

    hipMemsetAsync(ws, 0, 1024, stream);
    hipMemsetAsync(d_out, 0, (size_t)out_size * sizeof(float), stream);

    router_kernel<<<dim3(RTR_BLOCKS), dim3(256), 0, stream>>>(x, gw, topk_idx, topk_prob, pcount, pprob);
    scan_kernel<<<dim3(1), dim3(64), 0, stream>>>(pcount, pprob, counts, offsets, out + (size_t)NTOK * EMB);
    scatter_kernel<<<dim3(NTOK / 256), dim3(256), 0, stream>>>(topk_idx, topk_prob, offsets, cursor, row_tok, row_prob);
    cvt_pack<<<dim3((NTOK * EMB / 8) / 256), dim3(256), 0, stream>>>(x, xbf, NTOK * EMB / 8);

    const int wn8 = NEXP * HID * EMB / 8;   // 4,194,304
    cvt_pack<<<dim3(wn8 / 256), dim3(256), 0, stream>>>(w1, w1bf, wn8);
    cvt_pack<<<dim3(wn8 / 256), dim3(256), 0, stream>>>(w2, w2bf, wn8);
    gemm1_bf<<<dim3(HID / 128, 32, NEXP), dim3(256), 0, stream>>>(
        xbf, w1bf, b1, w2bf, b2, counts, offsets, row_tok, Hbuf);
    cvt_pack<<<dim3(wn8 / 256), dim3(256), 0, stream>>>(w3, w3bf, wn8);
    gemm2_bf<<<dim3(EMB / 128, 32, NEXP), dim3(256), 0, stream>>>(
        Hbuf, w3bf, b3, counts, offsets, row_tok, row_prob, out);
}